// Round 4
// baseline (1587.333 us; speedup 1.0000x reference)
//
#include <hip/hip_runtime.h>

#define D 64
#define K 512
#define NVEC 131072     // 8192 * 16
#define BLOCK 256
#define KSPLIT 4        // k-range slices (one per wave)
#define KSL (K / KSPLIT)
#define VPB 64          // vectors per block (one per lane)

// Kernel A: w2half[k] = 0.5 * |w_k|^2 ; also zero the loss slot.
__global__ __launch_bounds__(64) void vq_prep(const float* __restrict__ w,
                                              float* __restrict__ w2half,
                                              float* __restrict__ loss_slot) {
    int k = blockIdx.x * 64 + threadIdx.x;
    if (blockIdx.x == 0 && threadIdx.x == 0) loss_slot[0] = 0.0f;
    if (k < K) {
        const float4* wv = (const float4*)(w + k * D);
        float s0 = 0.f, s1 = 0.f, s2 = 0.f, s3 = 0.f;
#pragma unroll
        for (int i = 0; i < D / 4; ++i) {
            float4 t = wv[i];
            s0 = fmaf(t.x, t.x, s0);
            s1 = fmaf(t.y, t.y, s1);
            s2 = fmaf(t.z, t.z, s2);
            s3 = fmaf(t.w, t.w, s3);
        }
        w2half[k] = 0.5f * ((s0 + s1) + (s2 + s3));
    }
}

// Kernel B: 4 waves share 64 vectors; wave `wid` scans codes
// [wid*128, wid*128+128) for vector block*64+lane. Codebook row address is
// wave-uniform -> s_load broadcast (round-2 proven codegen); 6 waves/SIMD
// hide the scalar-load latency that limited round 2 at 2 waves/SIMD.
__global__ __launch_bounds__(BLOCK, 6) void vq_main(const float* __restrict__ z_all,
                                                    const float* __restrict__ w,
                                                    const float* __restrict__ w2half,
                                                    float* __restrict__ out,
                                                    float* __restrict__ loss_slot) {
    const int t = threadIdx.x;
    const int lane = t & 63;
    const int wid = t >> 6;                 // k-slice, wave-uniform
    const int v = blockIdx.x * VPB + lane;  // vector index

    // Load z (negated so the inner loop is a pure fma: acc += (-z)*w).
    const float4* zv = (const float4*)(z_all + (size_t)v * D);
    float zn[D];
#pragma unroll
    for (int i = 0; i < D / 4; ++i) {
        float4 tt = zv[i];
        zn[4 * i + 0] = -tt.x;
        zn[4 * i + 1] = -tt.y;
        zn[4 * i + 2] = -tt.z;
        zn[4 * i + 3] = -tt.w;
    }

    const int kbase = wid * KSL;
    float best = 3.402823466e+38f;
    int bidx = kbase;
    for (int kk = 0; kk < KSL; ++kk) {
        const int k = kbase + kk;
        const float* __restrict__ wk = w + k * D;   // wave-uniform -> s_load
        float a0 = w2half[k], a1 = 0.f, a2 = 0.f, a3 = 0.f;
#pragma unroll
        for (int dd = 0; dd < D; dd += 4) {
            a0 = fmaf(zn[dd + 0], wk[dd + 0], a0);
            a1 = fmaf(zn[dd + 1], wk[dd + 1], a1);
            a2 = fmaf(zn[dd + 2], wk[dd + 2], a2);
            a3 = fmaf(zn[dd + 3], wk[dd + 3], a3);
        }
        float s = (a0 + a1) + (a2 + a3);
        bool lt = s < best;             // strict < keeps first index (jnp.argmin)
        best = lt ? s : best;
        bidx = lt ? k : bidx;
    }

    // Combine the 4 k-slices per vector. Slices have disjoint increasing
    // k-ranges, so "(ob < best) || (ob == best && oi < bidx)" reproduces the
    // global first-min of a full scan.
    __shared__ float sbest[KSPLIT][VPB];
    __shared__ int   sidx[KSPLIT][VPB];
    sbest[wid][lane] = best;
    sidx[wid][lane] = bidx;
    __syncthreads();

    if (wid == 0) {
#pragma unroll
        for (int s2 = 1; s2 < KSPLIT; ++s2) {
            float ob = sbest[s2][lane];
            int oi = sidx[s2][lane];
            bool take = (ob < best) || (ob == best && oi < bidx);
            best = take ? ob : best;
            bidx = take ? oi : bidx;
        }

        // Epilogue (identical arithmetic to round 2, absmax was 0.0):
        // out = z + (q - z); loss accumulated elementwise as (q - z)^2.
        const float4* qv = (const float4*)(w + bidx * D);
        float4* ov = (float4*)(out + (size_t)v * D);
        float lsum = 0.f;
#pragma unroll
        for (int i = 0; i < D / 4; ++i) {
            float4 q = qv[i];
            float z0 = -zn[4 * i + 0], z1 = -zn[4 * i + 1];
            float z2 = -zn[4 * i + 2], z3 = -zn[4 * i + 3];
            float t0 = q.x - z0, t1 = q.y - z1, t2 = q.z - z2, t3 = q.w - z3;
            float4 o;
            o.x = z0 + t0;
            o.y = z1 + t1;
            o.z = z2 + t2;
            o.w = z3 + t3;
            ov[i] = o;
            lsum = fmaf(t0, t0, lsum);
            lsum = fmaf(t1, t1, lsum);
            lsum = fmaf(t2, t2, lsum);
            lsum = fmaf(t3, t3, lsum);
        }

        // Wave-0 reduction of the loss partial sums, one atomic per block.
#pragma unroll
        for (int off = 32; off > 0; off >>= 1) lsum += __shfl_down(lsum, off, 64);
        if (lane == 0) {
            // vq_loss = 1.25 * sum / (8192*16*64); 1.25/2^23 is exact in fp32.
            atomicAdd(loss_slot, lsum * (1.25f / 8388608.0f));
        }
    }
}

extern "C" void kernel_launch(void* const* d_in, const int* in_sizes, int n_in,
                              void* d_out, int out_size, void* d_ws, size_t ws_size,
                              hipStream_t stream) {
    const float* latents = (const float*)d_in[0];   // [8192, 1024] f32
    const float* weight  = (const float*)d_in[1];   // [512, 64] f32
    float* out = (float*)d_out;                     // 8388608 outputs + 1 loss
    float* loss_slot = out + (size_t)NVEC * D;
    float* w2half = (float*)d_ws;                   // 512 floats of scratch

    vq_prep<<<8, 64, 0, stream>>>(weight, w2half, loss_slot);
    vq_main<<<NVEC / VPB, BLOCK, 0, stream>>>(latents, weight, w2half, out, loss_slot);
}

// Round 5
// 584.558 us; speedup vs baseline: 2.7154x; 2.7154x over previous
//
#include <hip/hip_runtime.h>

#define D 64
#define K 512
#define NVEC 131072     // 8192 * 16
#define BLOCK 256
#define KSPLIT 4        // k-range slices (one per wave)
#define KSL (K / KSPLIT)
#define VPB 64          // vectors per block (one per lane)

// Kernel A: w2half[k] = 0.5 * |w_k|^2 ; also zero the loss slot.
__global__ __launch_bounds__(64) void vq_prep(const float* __restrict__ w,
                                              float* __restrict__ w2half,
                                              float* __restrict__ loss_slot) {
    int k = blockIdx.x * 64 + threadIdx.x;
    if (blockIdx.x == 0 && threadIdx.x == 0) loss_slot[0] = 0.0f;
    if (k < K) {
        const float4* wv = (const float4*)(w + k * D);
        float s0 = 0.f, s1 = 0.f, s2 = 0.f, s3 = 0.f;
#pragma unroll
        for (int i = 0; i < D / 4; ++i) {
            float4 t = wv[i];
            s0 = fmaf(t.x, t.x, s0);
            s1 = fmaf(t.y, t.y, s1);
            s2 = fmaf(t.z, t.z, s2);
            s3 = fmaf(t.w, t.w, s3);
        }
        w2half[k] = 0.5f * ((s0 + s1) + (s2 + s3));
    }
}

// Kernel B: 4 waves share 64 vectors; wave `wid` scans codes
// [wid*128, wid*128+128) for vector block*64+lane. Codebook row address is
// wave-uniform -> s_load broadcast. launch_bounds(256,4): VGPR cap 128 —
// round 4 proved that min-waves=6 caps VGPR at 40 and spills zn[64] to
// scratch (FETCH 3.4 GB, 6x slower). zn must stay in registers.
__global__ __launch_bounds__(BLOCK, 4) void vq_main(const float* __restrict__ z_all,
                                                    const float* __restrict__ w,
                                                    const float* __restrict__ w2half,
                                                    float* __restrict__ out,
                                                    float* __restrict__ loss_slot) {
    const int t = threadIdx.x;
    const int lane = t & 63;
    const int wid = t >> 6;                 // k-slice, wave-uniform
    const int v = blockIdx.x * VPB + lane;  // vector index

    // Load z (negated so the inner loop is a pure fma: acc += (-z)*w).
    const float4* zv = (const float4*)(z_all + (size_t)v * D);
    float zn[D];
#pragma unroll
    for (int i = 0; i < D / 4; ++i) {
        float4 tt = zv[i];
        zn[4 * i + 0] = -tt.x;
        zn[4 * i + 1] = -tt.y;
        zn[4 * i + 2] = -tt.z;
        zn[4 * i + 3] = -tt.w;
    }

    const int kbase = wid * KSL;
    float best = 3.402823466e+38f;
    int bidx = kbase;
    for (int kk = 0; kk < KSL; ++kk) {
        const int k = kbase + kk;
        const float* __restrict__ wk = w + k * D;   // wave-uniform -> s_load
        float a0 = w2half[k], a1 = 0.f, a2 = 0.f, a3 = 0.f;
#pragma unroll
        for (int dd = 0; dd < D; dd += 4) {
            a0 = fmaf(zn[dd + 0], wk[dd + 0], a0);
            a1 = fmaf(zn[dd + 1], wk[dd + 1], a1);
            a2 = fmaf(zn[dd + 2], wk[dd + 2], a2);
            a3 = fmaf(zn[dd + 3], wk[dd + 3], a3);
        }
        float s = (a0 + a1) + (a2 + a3);
        bool lt = s < best;             // strict < keeps first index (jnp.argmin)
        best = lt ? s : best;
        bidx = lt ? k : bidx;
    }

    // Combine the 4 k-slices per vector. Slices have disjoint increasing
    // k-ranges, so "(ob < best) || (ob == best && oi < bidx)" reproduces the
    // global first-min of a full scan.
    __shared__ float sbest[KSPLIT][VPB];
    __shared__ int   sidx[KSPLIT][VPB];
    sbest[wid][lane] = best;
    sidx[wid][lane] = bidx;
    __syncthreads();

    if (wid == 0) {
#pragma unroll
        for (int s2 = 1; s2 < KSPLIT; ++s2) {
            float ob = sbest[s2][lane];
            int oi = sidx[s2][lane];
            bool take = (ob < best) || (ob == best && oi < bidx);
            best = take ? ob : best;
            bidx = take ? oi : bidx;
        }

        // Epilogue (identical arithmetic to round 2, absmax was 0.0):
        // out = z + (q - z); loss accumulated elementwise as (q - z)^2.
        const float4* qv = (const float4*)(w + bidx * D);
        float4* ov = (float4*)(out + (size_t)v * D);
        float lsum = 0.f;
#pragma unroll
        for (int i = 0; i < D / 4; ++i) {
            float4 q = qv[i];
            float z0 = -zn[4 * i + 0], z1 = -zn[4 * i + 1];
            float z2 = -zn[4 * i + 2], z3 = -zn[4 * i + 3];
            float t0 = q.x - z0, t1 = q.y - z1, t2 = q.z - z2, t3 = q.w - z3;
            float4 o;
            o.x = z0 + t0;
            o.y = z1 + t1;
            o.z = z2 + t2;
            o.w = z3 + t3;
            ov[i] = o;
            lsum = fmaf(t0, t0, lsum);
            lsum = fmaf(t1, t1, lsum);
            lsum = fmaf(t2, t2, lsum);
            lsum = fmaf(t3, t3, lsum);
        }

        // Wave-0 reduction of the loss partial sums, one atomic per block.
#pragma unroll
        for (int off = 32; off > 0; off >>= 1) lsum += __shfl_down(lsum, off, 64);
        if (lane == 0) {
            // vq_loss = 1.25 * sum / (8192*16*64); 1.25/2^23 is exact in fp32.
            atomicAdd(loss_slot, lsum * (1.25f / 8388608.0f));
        }
    }
}

extern "C" void kernel_launch(void* const* d_in, const int* in_sizes, int n_in,
                              void* d_out, int out_size, void* d_ws, size_t ws_size,
                              hipStream_t stream) {
    const float* latents = (const float*)d_in[0];   // [8192, 1024] f32
    const float* weight  = (const float*)d_in[1];   // [512, 64] f32
    float* out = (float*)d_out;                     // 8388608 outputs + 1 loss
    float* loss_slot = out + (size_t)NVEC * D;
    float* w2half = (float*)d_ws;                   // 512 floats of scratch

    vq_prep<<<8, 64, 0, stream>>>(weight, w2half, loss_slot);
    vq_main<<<NVEC / VPB, BLOCK, 0, stream>>>(latents, weight, w2half, out, loss_slot);
}

// Round 7
// 553.614 us; speedup vs baseline: 2.8672x; 1.0559x over previous
//
#include <hip/hip_runtime.h>

#define D 64
#define K 512
#define NVEC 131072     // 8192 * 16
#define BLOCK 256
#define KSPLIT 4        // k-range slices (one per wave)
#define KSL (K / KSPLIT)
#define VPB 64          // vectors per block (one per lane)

// Kernel A: w2half[k] = 0.5 * |w_k|^2 ; also zero the loss slot.
__global__ __launch_bounds__(64) void vq_prep(const float* __restrict__ w,
                                              float* __restrict__ w2half,
                                              float* __restrict__ loss_slot) {
    int k = blockIdx.x * 64 + threadIdx.x;
    if (blockIdx.x == 0 && threadIdx.x == 0) loss_slot[0] = 0.0f;
    if (k < K) {
        const float4* wv = (const float4*)(w + k * D);
        float s0 = 0.f, s1 = 0.f, s2 = 0.f, s3 = 0.f;
#pragma unroll
        for (int i = 0; i < D / 4; ++i) {
            float4 t = wv[i];
            s0 = fmaf(t.x, t.x, s0);
            s1 = fmaf(t.y, t.y, s1);
            s2 = fmaf(t.z, t.z, s2);
            s3 = fmaf(t.w, t.w, s3);
        }
        w2half[k] = 0.5f * ((s0 + s1) + (s2 + s3));
    }
}

// Kernel B: 4 waves share 64 vectors; wave `wid` scans codes
// [wid*128, wid*128+128) for vector block*64+lane. Codebook row address is
// wave-uniform -> s_load broadcast.
// NO min-waves launch_bounds: rounds 4/5 proved any min-waves hint ((256,6)
// -> 40 VGPR, (256,4) -> 64 VGPR) caps VGPRs below the ~72 this body needs
// and spills zn[64] to scratch (WRITE_SIZE 135-242 MB, 2.3-6x slower).
// Plain (256) gave 72 VGPR / no spill in round 2; at 72 VGPR the HW still
// runs 4 waves/SIMD, and this grid (2048 blocks) supplies them.
__global__ __launch_bounds__(BLOCK) void vq_main(const float* __restrict__ z_all,
                                                 const float* __restrict__ w,
                                                 const float* __restrict__ w2half,
                                                 float* __restrict__ out,
                                                 float* __restrict__ loss_slot) {
    const int t = threadIdx.x;
    const int lane = t & 63;
    const int wid = t >> 6;                 // k-slice, wave-uniform
    const int v = blockIdx.x * VPB + lane;  // vector index

    // Load z (negated so the inner loop is a pure fma: acc += (-z)*w).
    const float4* zv = (const float4*)(z_all + (size_t)v * D);
    float zn[D];
#pragma unroll
    for (int i = 0; i < D / 4; ++i) {
        float4 tt = zv[i];
        zn[4 * i + 0] = -tt.x;
        zn[4 * i + 1] = -tt.y;
        zn[4 * i + 2] = -tt.z;
        zn[4 * i + 3] = -tt.w;
    }

    const int kbase = wid * KSL;
    float best = 3.402823466e+38f;
    int bidx = kbase;
    for (int kk = 0; kk < KSL; ++kk) {
        const int k = kbase + kk;
        const float* __restrict__ wk = w + k * D;   // wave-uniform -> s_load
        float a0 = w2half[k], a1 = 0.f, a2 = 0.f, a3 = 0.f;
#pragma unroll
        for (int dd = 0; dd < D; dd += 4) {
            a0 = fmaf(zn[dd + 0], wk[dd + 0], a0);
            a1 = fmaf(zn[dd + 1], wk[dd + 1], a1);
            a2 = fmaf(zn[dd + 2], wk[dd + 2], a2);
            a3 = fmaf(zn[dd + 3], wk[dd + 3], a3);
        }
        float s = (a0 + a1) + (a2 + a3);
        bool lt = s < best;             // strict < keeps first index (jnp.argmin)
        best = lt ? s : best;
        bidx = lt ? k : bidx;
    }

    // Combine the 4 k-slices per vector. Slices have disjoint increasing
    // k-ranges, so "(ob < best) || (ob == best && oi < bidx)" reproduces the
    // global first-min of a full scan.
    __shared__ float sbest[KSPLIT][VPB];
    __shared__ int   sidx[KSPLIT][VPB];
    sbest[wid][lane] = best;
    sidx[wid][lane] = bidx;
    __syncthreads();

    if (wid == 0) {
#pragma unroll
        for (int s2 = 1; s2 < KSPLIT; ++s2) {
            float ob = sbest[s2][lane];
            int oi = sidx[s2][lane];
            bool take = (ob < best) || (ob == best && oi < bidx);
            best = take ? ob : best;
            bidx = take ? oi : bidx;
        }

        // Epilogue (identical arithmetic to round 2, absmax was 0.0):
        // out = z + (q - z); loss accumulated elementwise as (q - z)^2.
        const float4* qv = (const float4*)(w + bidx * D);
        float4* ov = (float4*)(out + (size_t)v * D);
        float lsum = 0.f;
#pragma unroll
        for (int i = 0; i < D / 4; ++i) {
            float4 q = qv[i];
            float z0 = -zn[4 * i + 0], z1 = -zn[4 * i + 1];
            float z2 = -zn[4 * i + 2], z3 = -zn[4 * i + 3];
            float t0 = q.x - z0, t1 = q.y - z1, t2 = q.z - z2, t3 = q.w - z3;
            float4 o;
            o.x = z0 + t0;
            o.y = z1 + t1;
            o.z = z2 + t2;
            o.w = z3 + t3;
            ov[i] = o;
            lsum = fmaf(t0, t0, lsum);
            lsum = fmaf(t1, t1, lsum);
            lsum = fmaf(t2, t2, lsum);
            lsum = fmaf(t3, t3, lsum);
        }

        // Wave-0 reduction of the loss partial sums, one atomic per block.
#pragma unroll
        for (int off = 32; off > 0; off >>= 1) lsum += __shfl_down(lsum, off, 64);
        if (lane == 0) {
            // vq_loss = 1.25 * sum / (8192*16*64); 1.25/2^23 is exact in fp32.
            atomicAdd(loss_slot, lsum * (1.25f / 8388608.0f));
        }
    }
}

extern "C" void kernel_launch(void* const* d_in, const int* in_sizes, int n_in,
                              void* d_out, int out_size, void* d_ws, size_t ws_size,
                              hipStream_t stream) {
    const float* latents = (const float*)d_in[0];   // [8192, 1024] f32
    const float* weight  = (const float*)d_in[1];   // [512, 64] f32
    float* out = (float*)d_out;                     // 8388608 outputs + 1 loss
    float* loss_slot = out + (size_t)NVEC * D;
    float* w2half = (float*)d_ws;                   // 512 floats of scratch

    vq_prep<<<8, 64, 0, stream>>>(weight, w2half, loss_slot);
    vq_main<<<NVEC / VPB, BLOCK, 0, stream>>>(latents, weight, w2half, out, loss_slot);
}

// Round 8
// 239.943 us; speedup vs baseline: 6.6155x; 2.3073x over previous
//
#include <hip/hip_runtime.h>

#define D 64
#define K 512
#define NVEC 131072     // 8192 * 16
#define BLOCK 256
#define KSPLIT 4        // k-range slices (one per wave)
#define KSL (K / KSPLIT)
#define VPB 64          // vectors per block (one per lane)

// Kernel A: w2half[k] = 0.5 * |w_k|^2 ; also zero the loss slot.
__global__ __launch_bounds__(64) void vq_prep(const float* __restrict__ w,
                                              float* __restrict__ w2half,
                                              float* __restrict__ loss_slot) {
    int k = blockIdx.x * 64 + threadIdx.x;
    if (blockIdx.x == 0 && threadIdx.x == 0) loss_slot[0] = 0.0f;
    if (k < K) {
        const float4* wv = (const float4*)(w + k * D);
        float s0 = 0.f, s1 = 0.f, s2 = 0.f, s3 = 0.f;
#pragma unroll
        for (int i = 0; i < D / 4; ++i) {
            float4 t = wv[i];
            s0 = fmaf(t.x, t.x, s0);
            s1 = fmaf(t.y, t.y, s1);
            s2 = fmaf(t.z, t.z, s2);
            s3 = fmaf(t.w, t.w, s3);
        }
        w2half[k] = 0.5f * ((s0 + s1) + (s2 + s3));
    }
}

// Kernel B: 4 waves share 64 vectors; wave `wid` scans codes
// [wid*128, wid*128+128) for vector block*64+lane.
// CRITICAL (round 7 lesson): wid must go through readfirstlane — raw
// threadIdx.x>>6 is treated as divergent by the compiler, which then emits
// per-lane global_load for the codebook row (SGPR 96->32, VGPR 72->108,
// 2x slower). readfirstlane makes w + k*D provably wave-uniform -> s_load
// broadcast on the scalar pipe (round-2 proven codegen).
// NO min-waves launch_bounds: rounds 4/5 proved any min-waves hint caps
// VGPRs below the ~72 this body needs and spills zn[64] to scratch.
__global__ __launch_bounds__(BLOCK) void vq_main(const float* __restrict__ z_all,
                                                 const float* __restrict__ w,
                                                 const float* __restrict__ w2half,
                                                 float* __restrict__ out,
                                                 float* __restrict__ loss_slot) {
    const int t = threadIdx.x;
    const int lane = t & 63;
    const int wid = __builtin_amdgcn_readfirstlane(t >> 6);  // wave-uniform SGPR
    const int v = blockIdx.x * VPB + lane;  // vector index

    // Load z (negated so the inner loop is a pure fma: acc += (-z)*w).
    const float4* zv = (const float4*)(z_all + (size_t)v * D);
    float zn[D];
#pragma unroll
    for (int i = 0; i < D / 4; ++i) {
        float4 tt = zv[i];
        zn[4 * i + 0] = -tt.x;
        zn[4 * i + 1] = -tt.y;
        zn[4 * i + 2] = -tt.z;
        zn[4 * i + 3] = -tt.w;
    }

    const int kbase = wid * KSL;
    float best = 3.402823466e+38f;
    int bidx = kbase;
    for (int kk = 0; kk < KSL; ++kk) {
        const int k = kbase + kk;
        const float* __restrict__ wk = w + k * D;   // wave-uniform -> s_load
        float a0 = w2half[k], a1 = 0.f, a2 = 0.f, a3 = 0.f;
#pragma unroll
        for (int dd = 0; dd < D; dd += 4) {
            a0 = fmaf(zn[dd + 0], wk[dd + 0], a0);
            a1 = fmaf(zn[dd + 1], wk[dd + 1], a1);
            a2 = fmaf(zn[dd + 2], wk[dd + 2], a2);
            a3 = fmaf(zn[dd + 3], wk[dd + 3], a3);
        }
        float s = (a0 + a1) + (a2 + a3);
        bool lt = s < best;             // strict < keeps first index (jnp.argmin)
        best = lt ? s : best;
        bidx = lt ? k : bidx;
    }

    // Combine the 4 k-slices per vector. Slices have disjoint increasing
    // k-ranges, so "(ob < best) || (ob == best && oi < bidx)" reproduces the
    // global first-min of a full scan.
    __shared__ float sbest[KSPLIT][VPB];
    __shared__ int   sidx[KSPLIT][VPB];
    sbest[wid][lane] = best;
    sidx[wid][lane] = bidx;
    __syncthreads();

    if (wid == 0) {
#pragma unroll
        for (int s2 = 1; s2 < KSPLIT; ++s2) {
            float ob = sbest[s2][lane];
            int oi = sidx[s2][lane];
            bool take = (ob < best) || (ob == best && oi < bidx);
            best = take ? ob : best;
            bidx = take ? oi : bidx;
        }

        // Epilogue (identical arithmetic to round 2, absmax was 0.0):
        // out = z + (q - z); loss accumulated elementwise as (q - z)^2.
        const float4* qv = (const float4*)(w + bidx * D);
        float4* ov = (float4*)(out + (size_t)v * D);
        float lsum = 0.f;
#pragma unroll
        for (int i = 0; i < D / 4; ++i) {
            float4 q = qv[i];
            float z0 = -zn[4 * i + 0], z1 = -zn[4 * i + 1];
            float z2 = -zn[4 * i + 2], z3 = -zn[4 * i + 3];
            float t0 = q.x - z0, t1 = q.y - z1, t2 = q.z - z2, t3 = q.w - z3;
            float4 o;
            o.x = z0 + t0;
            o.y = z1 + t1;
            o.z = z2 + t2;
            o.w = z3 + t3;
            ov[i] = o;
            lsum = fmaf(t0, t0, lsum);
            lsum = fmaf(t1, t1, lsum);
            lsum = fmaf(t2, t2, lsum);
            lsum = fmaf(t3, t3, lsum);
        }

        // Wave-0 reduction of the loss partial sums, one atomic per block.
#pragma unroll
        for (int off = 32; off > 0; off >>= 1) lsum += __shfl_down(lsum, off, 64);
        if (lane == 0) {
            // vq_loss = 1.25 * sum / (8192*16*64); 1.25/2^23 is exact in fp32.
            atomicAdd(loss_slot, lsum * (1.25f / 8388608.0f));
        }
    }
}

extern "C" void kernel_launch(void* const* d_in, const int* in_sizes, int n_in,
                              void* d_out, int out_size, void* d_ws, size_t ws_size,
                              hipStream_t stream) {
    const float* latents = (const float*)d_in[0];   // [8192, 1024] f32
    const float* weight  = (const float*)d_in[1];   // [512, 64] f32
    float* out = (float*)d_out;                     // 8388608 outputs + 1 loss
    float* loss_slot = out + (size_t)NVEC * D;
    float* w2half = (float*)d_ws;                   // 512 floats of scratch

    vq_prep<<<8, 64, 0, stream>>>(weight, w2half, loss_slot);
    vq_main<<<NVEC / VPB, BLOCK, 0, stream>>>(latents, weight, w2half, out, loss_slot);
}